// Round 1
// baseline (3085.912 us; speedup 1.0000x reference)
//
#include <hip/hip_runtime.h>

// Problem constants (reference: N=100000, D=32, E=1600000, EH=32, NH=16, TAU=0.1)
#define D_FEAT 32
#define IN_DIM 34   // D + 2
#define EHID 32
#define NHID 16
#define INV_TAU 10.0f

// ---------- float <-> ordered-uint encoding for atomicMax on floats ----------
__device__ __forceinline__ unsigned enc_f32(float f) {
    unsigned b = __float_as_uint(f);
    return (b & 0x80000000u) ? ~b : (b | 0x80000000u);
}
__device__ __forceinline__ float dec_f32(unsigned e) {
    unsigned b = (e & 0x80000000u) ? (e & 0x7fffffffu) : ~e;
    return __uint_as_float(b);
}

// ---------- K1: hsd sum / sumsq reduction (double accumulation) ----------
__global__ __launch_bounds__(256) void k1_hsd_stats(const float* __restrict__ hsd,
                                                    double* __restrict__ stats, int N) {
    double s = 0.0, s2 = 0.0;
    for (int i = blockIdx.x * 256 + threadIdx.x; i < N; i += gridDim.x * 256) {
        double v = (double)hsd[i];
        s += v; s2 += v * v;
    }
    // wave (64-lane) reduce
    for (int off = 32; off > 0; off >>= 1) {
        s  += __shfl_down(s,  off, 64);
        s2 += __shfl_down(s2, off, 64);
    }
    __shared__ double ls[4], ls2[4];
    int wid = threadIdx.x >> 6, lid = threadIdx.x & 63;
    if (lid == 0) { ls[wid] = s; ls2[wid] = s2; }
    __syncthreads();
    if (threadIdx.x == 0) {
        double ts = 0.0, t2 = 0.0;
        for (int w = 0; w < 4; ++w) { ts += ls[w]; t2 += ls2[w]; }
        atomicAdd(stats, ts);
        atomicAdd(stats + 1, t2);
    }
}

// ---------- K2: per-node hsd_norm + gate alpha_bar ----------
__global__ __launch_bounds__(256) void k2_node_prep(const float* __restrict__ hsd,
                                                    const double* __restrict__ stats,
                                                    const float* __restrict__ Wn1,
                                                    const float* __restrict__ bn1,
                                                    const float* __restrict__ Wn2,
                                                    const float* __restrict__ bn2,
                                                    float* __restrict__ hsd_norm,
                                                    float* __restrict__ alpha_bar, int N) {
    int n = blockIdx.x * 256 + threadIdx.x;
    if (n >= N) return;
    double sum = stats[0], sumsq = stats[1];
    double mean = sum / (double)N;
    double var  = (sumsq - sum * sum / (double)N) / (double)(N - 1);
    float stdv  = (float)sqrt(var);
    float hn = (hsd[n] - (float)mean) / (stdv + 1e-8f);
    hsd_norm[n] = hn;
    float acc = bn2[0];
#pragma unroll
    for (int k = 0; k < NHID; ++k)
        acc += fmaxf(fmaf(hn, Wn1[k], bn1[k]), 0.0f) * Wn2[k];
    alpha_bar[n] = 1.0f / (1.0f + __expf(-acc));
}

// ---------- K3: edge MLP -> logits, seg-max, degree counts ----------
__global__ __launch_bounds__(256) void k3_edge_mlp(const float* __restrict__ x,
                                                   const float* __restrict__ hsd_norm,
                                                   const float* __restrict__ We1,
                                                   const float* __restrict__ be1,
                                                   const float* __restrict__ We2,
                                                   const float* __restrict__ be2,
                                                   const int* __restrict__ ei,
                                                   unsigned* __restrict__ seg_max_enc,
                                                   float* __restrict__ src_cnt,
                                                   float* __restrict__ dst_cnt,
                                                   float* __restrict__ exlog, int E) {
    int e = blockIdx.x * 256 + threadIdx.x;
    if (e >= E) return;
    int u = ei[e];
    int v = ei[E + e];

    float in[IN_DIM];
    in[0] = hsd_norm[u];
    in[1] = hsd_norm[v];
    const float4* xu = (const float4*)(x + (size_t)u * D_FEAT);
    const float4* xv = (const float4*)(x + (size_t)v * D_FEAT);
#pragma unroll
    for (int q = 0; q < 8; ++q) {
        float4 a = xu[q], b = xv[q];
        in[2 + 4 * q + 0] = fabsf(a.x - b.x);
        in[2 + 4 * q + 1] = fabsf(a.y - b.y);
        in[2 + 4 * q + 2] = fabsf(a.z - b.z);
        in[2 + 4 * q + 3] = fabsf(a.w - b.w);
    }

    float h[EHID];
#pragma unroll
    for (int j = 0; j < EHID; ++j) h[j] = be1[j];
#pragma unroll
    for (int i = 0; i < IN_DIM; ++i) {
        float a = in[i];
#pragma unroll
        for (int j = 0; j < EHID; ++j)
            h[j] = fmaf(a, We1[i * EHID + j], h[j]);   // uniform index -> s_load operand
    }
    float acc = be2[0];
#pragma unroll
    for (int j = 0; j < EHID; ++j)
        acc += fmaxf(h[j], 0.0f) * We2[j];

    float logit = acc * INV_TAU;
    exlog[e] = logit;
    atomicMax(seg_max_enc + v, enc_f32(logit));
    atomicAdd(src_cnt + u, 1.0f);
    atomicAdd(dst_cnt + v, 1.0f);
}

// ---------- K4: ex = exp(logit - segmax), denom accumulation ----------
__global__ __launch_bounds__(256) void k4_edge_exp(const int* __restrict__ ei,
                                                   const unsigned* __restrict__ seg_max_enc,
                                                   float* __restrict__ exlog,
                                                   float* __restrict__ denom, int E) {
    int e = blockIdx.x * 256 + threadIdx.x;
    if (e >= E) return;
    int v = ei[E + e];
    float m = dec_f32(seg_max_enc[v]);
    float ex = __expf(exlog[e] - m);
    exlog[e] = ex;
    atomicAdd(denom + v, ex);
}

// ---------- K5: edge scatter out[v] += coef * x[u] ----------
__global__ __launch_bounds__(256) void k5_edge_scatter(const float* __restrict__ x,
                                                       const int* __restrict__ ei,
                                                       const float* __restrict__ exlog,
                                                       const float* __restrict__ denom,
                                                       const float* __restrict__ src_cnt,
                                                       const float* __restrict__ dst_cnt,
                                                       const float* __restrict__ alpha_bar,
                                                       float* __restrict__ out, int E) {
    int e = blockIdx.x * 256 + threadIdx.x;
    if (e >= E) return;
    int u = ei[e];
    int v = ei[E + e];
    float alpha = exlog[e] / (denom[v] + 1e-16f);
    float sdu = sqrtf(fmaxf(src_cnt[u], 1.0f));
    float sdv = sqrtf(fmaxf(dst_cnt[v], 1.0f));
    float ew = 1.0f / (sdu * sdv);
    float ab = alpha_bar[v];
    float coef = (1.0f - ab) * ew - ab * alpha;

    const float4* xu = (const float4*)(x + (size_t)u * D_FEAT);
    float* o = out + (size_t)v * D_FEAT;
#pragma unroll
    for (int q = 0; q < 8; ++q) {
        float4 a = xu[q];
        atomicAdd(o + 4 * q + 0, coef * a.x);
        atomicAdd(o + 4 * q + 1, coef * a.y);
        atomicAdd(o + 4 * q + 2, coef * a.z);
        atomicAdd(o + 4 * q + 3, coef * a.w);
    }
}

// ---------- K6: out[v] += ab * S * x[v] ----------
__global__ __launch_bounds__(256) void k6_node_final(const float* __restrict__ x,
                                                     const float* __restrict__ denom,
                                                     const float* __restrict__ alpha_bar,
                                                     float* __restrict__ out, int N) {
    int t = blockIdx.x * 256 + threadIdx.x;
    if (t >= N * D_FEAT) return;
    int n = t >> 5;
    float dn = denom[n];
    float s = dn / (dn + 1e-16f);
    out[t] += alpha_bar[n] * s * x[t];
}

extern "C" void kernel_launch(void* const* d_in, const int* in_sizes, int n_in,
                              void* d_out, int out_size, void* d_ws, size_t ws_size,
                              hipStream_t stream) {
    const float* x    = (const float*)d_in[0];
    const float* hsd  = (const float*)d_in[1];
    const float* We1  = (const float*)d_in[2];
    const float* be1  = (const float*)d_in[3];
    const float* We2  = (const float*)d_in[4];
    const float* be2  = (const float*)d_in[5];
    const float* Wn1  = (const float*)d_in[6];
    const float* bn1  = (const float*)d_in[7];
    const float* Wn2  = (const float*)d_in[8];
    const float* bn2  = (const float*)d_in[9];
    const int*   ei   = (const int*)d_in[10];
    float* out = (float*)d_out;

    const int N = in_sizes[1];
    const int E = in_sizes[10] / 2;

    // ws layout (bytes):
    //  [0, 64):            double stats[2]
    //  [64, 64+4N):        unsigned seg_max_enc[N]
    //  [64+4N, 64+8N):     float denom[N]
    //  [64+8N, 64+12N):    float src_cnt[N]
    //  [64+12N, 64+16N):   float dst_cnt[N]
    //  [64+16N, 64+20N):   float hsd_norm[N]
    //  [64+20N, 64+24N):   float alpha_bar[N]
    //  [64+24N, ...):      float exlog[E]
    char* ws = (char*)d_ws;
    double*   stats       = (double*)ws;
    unsigned* seg_max_enc = (unsigned*)(ws + 64);
    float*    denom       = (float*)(ws + 64 + (size_t)4 * N);
    float*    src_cnt     = (float*)(ws + 64 + (size_t)8 * N);
    float*    dst_cnt     = (float*)(ws + 64 + (size_t)12 * N);
    float*    hsd_norm    = (float*)(ws + 64 + (size_t)16 * N);
    float*    alpha_bar   = (float*)(ws + 64 + (size_t)20 * N);
    float*    exlog       = (float*)(ws + 64 + (size_t)24 * N);

    // zero: stats + seg_max_enc + denom + src_cnt + dst_cnt, and the output
    hipMemsetAsync(d_ws, 0, 64 + (size_t)16 * N, stream);
    hipMemsetAsync(d_out, 0, (size_t)out_size * sizeof(float), stream);

    k1_hsd_stats<<<256, 256, 0, stream>>>(hsd, stats, N);
    k2_node_prep<<<(N + 255) / 256, 256, 0, stream>>>(hsd, stats, Wn1, bn1, Wn2, bn2,
                                                      hsd_norm, alpha_bar, N);
    int eblocks = (E + 255) / 256;
    k3_edge_mlp<<<eblocks, 256, 0, stream>>>(x, hsd_norm, We1, be1, We2, be2, ei,
                                             seg_max_enc, src_cnt, dst_cnt, exlog, E);
    k4_edge_exp<<<eblocks, 256, 0, stream>>>(ei, seg_max_enc, exlog, denom, E);
    k5_edge_scatter<<<eblocks, 256, 0, stream>>>(x, ei, exlog, denom, src_cnt, dst_cnt,
                                                 alpha_bar, out, E);
    k6_node_final<<<(N * D_FEAT + 255) / 256, 256, 0, stream>>>(x, denom, alpha_bar, out, N);
}

// Round 2
// 489.748 us; speedup vs baseline: 6.3010x; 6.3010x over previous
//
#include <hip/hip_runtime.h>

// Problem constants (reference: N=100000, D=32, E=1600000, EH=32, NH=16, TAU=0.1)
#define D_FEAT 32
#define IN_DIM 34   // D + 2
#define EHID 32
#define NHID 16
#define INV_TAU 10.0f
#define SCAN_CHUNK 1024

// ---------- K1: hsd sum / sumsq reduction (double accumulation) ----------
__global__ __launch_bounds__(256) void k1_hsd_stats(const float* __restrict__ hsd,
                                                    double* __restrict__ stats, int N) {
    double s = 0.0, s2 = 0.0;
    for (int i = blockIdx.x * 256 + threadIdx.x; i < N; i += gridDim.x * 256) {
        double v = (double)hsd[i];
        s += v; s2 += v * v;
    }
    for (int off = 32; off > 0; off >>= 1) {
        s  += __shfl_down(s,  off, 64);
        s2 += __shfl_down(s2, off, 64);
    }
    __shared__ double ls[4], ls2[4];
    int wid = threadIdx.x >> 6, lid = threadIdx.x & 63;
    if (lid == 0) { ls[wid] = s; ls2[wid] = s2; }
    __syncthreads();
    if (threadIdx.x == 0) {
        double ts = 0.0, t2 = 0.0;
        for (int w = 0; w < 4; ++w) { ts += ls[w]; t2 += ls2[w]; }
        atomicAdd(stats, ts);
        atomicAdd(stats + 1, t2);
    }
}

// ---------- K2: per-node hsd_norm + gate alpha_bar ----------
__global__ __launch_bounds__(256) void k2_node_prep(const float* __restrict__ hsd,
                                                    const double* __restrict__ stats,
                                                    const float* __restrict__ Wn1,
                                                    const float* __restrict__ bn1,
                                                    const float* __restrict__ Wn2,
                                                    const float* __restrict__ bn2,
                                                    float* __restrict__ hsd_norm,
                                                    float* __restrict__ alpha_bar, int N) {
    int n = blockIdx.x * 256 + threadIdx.x;
    if (n >= N) return;
    double sum = stats[0], sumsq = stats[1];
    double mean = sum / (double)N;
    double var  = (sumsq - sum * sum / (double)N) / (double)(N - 1);
    float stdv  = (float)sqrt(var);
    float hn = (hsd[n] - (float)mean) / (stdv + 1e-8f);
    hsd_norm[n] = hn;
    float acc = bn2[0];
#pragma unroll
    for (int k = 0; k < NHID; ++k)
        acc += fmaxf(fmaf(hn, Wn1[k], bn1[k]), 0.0f) * Wn2[k];
    alpha_bar[n] = 1.0f / (1.0f + __expf(-acc));
}

// ---------- K3: edge MLP -> logit; int degree counts ----------
__global__ __launch_bounds__(256) void k3_edge_mlp(const float* __restrict__ x,
                                                   const float* __restrict__ hsd_norm,
                                                   const float* __restrict__ We1,
                                                   const float* __restrict__ be1,
                                                   const float* __restrict__ We2,
                                                   const float* __restrict__ be2,
                                                   const int* __restrict__ ei,
                                                   int* __restrict__ src_cnt,
                                                   int* __restrict__ dst_cnt,
                                                   float* __restrict__ logit, int E) {
    int e = blockIdx.x * 256 + threadIdx.x;
    if (e >= E) return;
    int u = ei[e];
    int v = ei[E + e];

    float in[IN_DIM];
    in[0] = hsd_norm[u];
    in[1] = hsd_norm[v];
    const float4* xu = (const float4*)(x + (size_t)u * D_FEAT);
    const float4* xv = (const float4*)(x + (size_t)v * D_FEAT);
#pragma unroll
    for (int q = 0; q < 8; ++q) {
        float4 a = xu[q], b = xv[q];
        in[2 + 4 * q + 0] = fabsf(a.x - b.x);
        in[2 + 4 * q + 1] = fabsf(a.y - b.y);
        in[2 + 4 * q + 2] = fabsf(a.z - b.z);
        in[2 + 4 * q + 3] = fabsf(a.w - b.w);
    }

    float h[EHID];
#pragma unroll
    for (int j = 0; j < EHID; ++j) h[j] = be1[j];
#pragma unroll
    for (int i = 0; i < IN_DIM; ++i) {
        float a = in[i];
#pragma unroll
        for (int j = 0; j < EHID; ++j)
            h[j] = fmaf(a, We1[i * EHID + j], h[j]);   // uniform weight idx -> scalar operand
    }
    float acc = be2[0];
#pragma unroll
    for (int j = 0; j < EHID; ++j)
        acc += fmaxf(h[j], 0.0f) * We2[j];

    logit[e] = acc * INV_TAU;
    atomicAdd(src_cnt + u, 1);
    atomicAdd(dst_cnt + v, 1);
}

// ---------- Scan (3 kernels): dst_cnt -> exclusive offsets dst_off[N+1] ----------
__global__ __launch_bounds__(256) void scan_k1(const int* __restrict__ cnt,
                                               int* __restrict__ out,
                                               int* __restrict__ partials, int N) {
    __shared__ int lds[256];
    int base = blockIdx.x * SCAN_CHUNK;
    int t = threadIdx.x;
    int v[4]; int loc = 0;
#pragma unroll
    for (int k = 0; k < 4; ++k) {
        int idx = base + t * 4 + k;
        v[k] = (idx < N) ? cnt[idx] : 0;
        loc += v[k];
    }
    lds[t] = loc; __syncthreads();
    for (int off = 1; off < 256; off <<= 1) {
        int a = (t >= off) ? lds[t - off] : 0;
        __syncthreads();
        lds[t] += a;
        __syncthreads();
    }
    int run = (t > 0) ? lds[t - 1] : 0;
    if (t == 255) partials[blockIdx.x] = lds[255];
#pragma unroll
    for (int k = 0; k < 4; ++k) {
        run += v[k];
        int idx = base + t * 4 + k;
        if (idx < N) out[idx + 1] = run;   // inclusive at idx -> slot idx+1
    }
    if (blockIdx.x == 0 && t == 0) out[0] = 0;
}

__global__ __launch_bounds__(256) void scan_k2(int* __restrict__ partials, int B) {
    __shared__ int lds[256];
    int t = threadIdx.x;
    lds[t] = (t < B) ? partials[t] : 0;
    __syncthreads();
    for (int off = 1; off < 256; off <<= 1) {
        int a = (t >= off) ? lds[t - off] : 0;
        __syncthreads();
        lds[t] += a;
        __syncthreads();
    }
    if (t < B) partials[t] = (t > 0) ? lds[t - 1] : 0;  // exclusive
}

__global__ __launch_bounds__(256) void scan_k3(int* __restrict__ out,
                                               const int* __restrict__ partials, int N) {
    int i = blockIdx.x * 256 + threadIdx.x;
    if (i >= N) return;
    out[i + 1] += partials[i / SCAN_CHUNK];
}

// ---------- K4r: counting-sort reorder by destination ----------
__global__ __launch_bounds__(256) void k4_reorder(const int* __restrict__ ei,
                                                  const float* __restrict__ logit,
                                                  const int* __restrict__ dst_off,
                                                  int* __restrict__ cursor,
                                                  int* __restrict__ src_sorted,
                                                  float* __restrict__ logit_sorted, int E) {
    int e = blockIdx.x * 256 + threadIdx.x;
    if (e >= E) return;
    int v = ei[E + e];
    int slot = dst_off[v] + atomicAdd(cursor + v, 1);
    src_sorted[slot] = ei[e];
    logit_sorted[slot] = logit[e];
}

// ---------- K5g: per-node gather aggregation (one wave per node) ----------
__global__ __launch_bounds__(256) void k5_gather(const float* __restrict__ x,
                                                 const int* __restrict__ dst_off,
                                                 const int* __restrict__ src_sorted,
                                                 const float* __restrict__ logit_sorted,
                                                 const int* __restrict__ src_cnt,
                                                 const int* __restrict__ dst_cnt,
                                                 const float* __restrict__ alpha_bar,
                                                 float* __restrict__ out, int N) {
    int wid = threadIdx.x >> 6;
    int lane = threadIdx.x & 63;
    int v = blockIdx.x * 4 + wid;
    if (v >= N) return;

    int beg = dst_off[v], end = dst_off[v + 1];

    // phase 1: segment max then denom (lanes parallel over edges)
    float m = -INFINITY;
    for (int j = beg + lane; j < end; j += 64) m = fmaxf(m, logit_sorted[j]);
#pragma unroll
    for (int off = 1; off < 64; off <<= 1) m = fmaxf(m, __shfl_xor(m, off, 64));
    float s = 0.0f;
    for (int j = beg + lane; j < end; j += 64) s += __expf(logit_sorted[j] - m);
#pragma unroll
    for (int off = 1; off < 64; off <<= 1) s += __shfl_xor(s, off, 64);
    float denom = s;

    float ab = alpha_bar[v];
    float sdv = sqrtf(fmaxf((float)(end - beg), 1.0f));
    int half = lane >> 5;
    int d = lane & 31;

    // phase 2: each 32-lane half processes one edge at a time
    float acc = 0.0f;
    for (int j = beg + half; j < end; j += 2) {
        int u = src_sorted[j];
        float lg = logit_sorted[j];
        float alpha = __expf(lg - m) / (denom + 1e-16f);
        float su = sqrtf(fmaxf((float)src_cnt[u], 1.0f));
        float ew = 1.0f / (su * sdv);
        float coef = (1.0f - ab) * ew - ab * alpha;
        acc = fmaf(coef, x[(size_t)u * D_FEAT + d], acc);
    }
    acc += __shfl_xor(acc, 32, 64);

    if (half == 0) {
        float S = denom / (denom + 1e-16f);   // = sum(alpha); 0 if deg==0
        float selfc = ab * S;
        out[(size_t)v * D_FEAT + d] = fmaf(selfc, x[(size_t)v * D_FEAT + d], acc);
    }
}

extern "C" void kernel_launch(void* const* d_in, const int* in_sizes, int n_in,
                              void* d_out, int out_size, void* d_ws, size_t ws_size,
                              hipStream_t stream) {
    const float* x    = (const float*)d_in[0];
    const float* hsd  = (const float*)d_in[1];
    const float* We1  = (const float*)d_in[2];
    const float* be1  = (const float*)d_in[3];
    const float* We2  = (const float*)d_in[4];
    const float* be2  = (const float*)d_in[5];
    const float* Wn1  = (const float*)d_in[6];
    const float* bn1  = (const float*)d_in[7];
    const float* Wn2  = (const float*)d_in[8];
    const float* bn2  = (const float*)d_in[9];
    const int*   ei   = (const int*)d_in[10];
    float* out = (float*)d_out;

    const int N = in_sizes[1];
    const int E = in_sizes[10] / 2;

    // ws layout (bytes), zeroed region first:
    //  [0,64)                       double stats[2]
    //  [64, +4N)                    int dst_cnt[N]
    //  [+4N, +8N)                   int src_cnt[N]
    //  [+8N, +12N)                  int cursor[N]
    //  ---- end of memset region ----
    //  [+12N, +16N+4)               int dst_off[N+1]
    //  [..., +1024)                 int partials[256]
    //  float hsd_norm[N], alpha_bar[N]
    //  float logit[E]; int src_sorted[E]; float logit_sorted[E]
    char* ws = (char*)d_ws;
    double* stats        = (double*)ws;
    int*    dst_cnt      = (int*)(ws + 64);
    int*    src_cnt      = (int*)(ws + 64 + (size_t)4 * N);
    int*    cursor       = (int*)(ws + 64 + (size_t)8 * N);
    int*    dst_off      = (int*)(ws + 64 + (size_t)12 * N);
    int*    partials     = (int*)(ws + 64 + (size_t)16 * N + 64);
    float*  hsd_norm     = (float*)(ws + 64 + (size_t)16 * N + 64 + 1024);
    float*  alpha_bar    = (float*)(ws + 64 + (size_t)20 * N + 64 + 1024);
    float*  logit        = (float*)(ws + 64 + (size_t)24 * N + 64 + 1024);
    int*    src_sorted   = (int*)(ws + 64 + (size_t)24 * N + 64 + 1024 + (size_t)4 * E);
    float*  logit_sorted = (float*)(ws + 64 + (size_t)24 * N + 64 + 1024 + (size_t)8 * E);

    hipMemsetAsync(d_ws, 0, 64 + (size_t)12 * N, stream);

    k1_hsd_stats<<<256, 256, 0, stream>>>(hsd, stats, N);
    k2_node_prep<<<(N + 255) / 256, 256, 0, stream>>>(hsd, stats, Wn1, bn1, Wn2, bn2,
                                                      hsd_norm, alpha_bar, N);
    int eblocks = (E + 255) / 256;
    k3_edge_mlp<<<eblocks, 256, 0, stream>>>(x, hsd_norm, We1, be1, We2, be2, ei,
                                             src_cnt, dst_cnt, logit, E);
    int B = (N + SCAN_CHUNK - 1) / SCAN_CHUNK;   // 98 <= 256
    scan_k1<<<B, 256, 0, stream>>>(dst_cnt, dst_off, partials, N);
    scan_k2<<<1, 256, 0, stream>>>(partials, B);
    scan_k3<<<(N + 255) / 256, 256, 0, stream>>>(dst_off, partials, N);
    k4_reorder<<<eblocks, 256, 0, stream>>>(ei, logit, dst_off, cursor,
                                            src_sorted, logit_sorted, E);
    k5_gather<<<(N + 3) / 4, 256, 0, stream>>>(x, dst_off, src_sorted, logit_sorted,
                                               src_cnt, dst_cnt, alpha_bar, out, N);
}